// Round 6
// baseline (6494.355 us; speedup 1.0000x reference)
//
#include <hip/hip_runtime.h>
#include <math.h>

#define D 64
#define NB_SCAN 256

__device__ __forceinline__ float elu_apply(float v, float sc, float sh) {
  v = v * sc + sh;
  return v > 0.f ? v : __expf(v) - 1.f;
}

// ---------------- degree histogram (int) ----------------
__global__ void hist_kernel(const int* __restrict__ dst, int* __restrict__ hist, int E) {
  int i = blockIdx.x * blockDim.x + threadIdx.x;
  int stride = gridDim.x * blockDim.x;
  for (int e = i; e < E; e += stride) atomicAdd(&hist[dst[e]], 1);
}

// ---------------- 3-pass scan ----------------
__global__ void scanA_kernel(const int* __restrict__ hist, int* __restrict__ blocksum, int N) {
  __shared__ int red[256];
  int b = blockIdx.x, t = threadIdx.x;
  int chunk = (N + NB_SCAN - 1) / NB_SCAN;
  int beg = b * chunk;
  int end = min(beg + chunk, N);
  int s = 0;
  for (int i = beg + t; i < end; i += 256) s += hist[i];
  red[t] = s;
  __syncthreads();
  for (int off = 128; off > 0; off >>= 1) {
    if (t < off) red[t] += red[t + off];
    __syncthreads();
  }
  if (t == 0) blocksum[b] = red[0];
}

__global__ void scanB_kernel(const int* __restrict__ blocksum, int* __restrict__ blockoff,
                             int* __restrict__ rowptr_last) {
  __shared__ int sm[NB_SCAN];
  int t = threadIdx.x;
  sm[t] = blocksum[t];
  __syncthreads();
  for (int off = 1; off < NB_SCAN; off <<= 1) {
    int v = (t >= off) ? sm[t - off] : 0;
    __syncthreads();
    sm[t] += v;
    __syncthreads();
  }
  blockoff[t] = (t == 0) ? 0 : sm[t - 1];
  if (t == NB_SCAN - 1) rowptr_last[0] = sm[t];
}

__global__ void scanC_kernel(const int* __restrict__ hist, const int* __restrict__ blockoff,
                             int* __restrict__ rowptr, float* __restrict__ degf, int N) {
  __shared__ int sm[256];
  int b = blockIdx.x, t = threadIdx.x;
  int chunk = (N + NB_SCAN - 1) / NB_SCAN;
  int beg = b * chunk;
  int end = min(beg + chunk, N);
  int sub = (chunk + 255) / 256;
  int mybeg = beg + t * sub;
  int myend = min(mybeg + sub, end);
  int s = 0;
  for (int i = mybeg; i < myend; ++i) s += hist[i];
  sm[t] = s;
  __syncthreads();
  for (int off = 1; off < 256; off <<= 1) {
    int v = (t >= off) ? sm[t - off] : 0;
    __syncthreads();
    sm[t] += v;
    __syncthreads();
  }
  int run = blockoff[b] + ((t == 0) ? 0 : sm[t - 1]);
  for (int i = mybeg; i < myend; ++i) {
    int h = hist[i];
    rowptr[i] = run;
    degf[i] = (float)h;
    run += h;
  }
}

// ---------------- CSR fill ----------------
__global__ void fill_kernel(const int* __restrict__ src, const int* __restrict__ dst,
                            const int* __restrict__ rowptr, int* __restrict__ cursor,
                            int* __restrict__ csr_src, int E) {
  int i = blockIdx.x * blockDim.x + threadIdx.x;
  int stride = gridDim.x * blockDim.x;
  for (int e = i; e < E; e += stride) {
    int d = dst[e];
    int pos = atomicAdd(&cursor[d], 1);
    csr_src[rowptr[d] + pos] = src[e];
  }
}

// ------- gather-sum with optional fused BN+ELU on gathered rows -------
template <int APPLY>
__global__ void gather_kernel(const float* __restrict__ h, const float* __restrict__ coef,
                              const int* __restrict__ rowptr, const int* __restrict__ csr_src,
                              float* __restrict__ agg, int N) {
  int lane = threadIdx.x & 63;
  int wid = (blockIdx.x * blockDim.x + threadIdx.x) >> 6;
  int nw = (gridDim.x * blockDim.x) >> 6;
  float sc = 1.f, sh = 0.f;
  if constexpr (APPLY) { sc = coef[lane]; sh = coef[D + lane]; }
  for (int n = wid; n < N; n += nw) {
    int beg = __builtin_amdgcn_readfirstlane(rowptr[n]);
    int end = __builtin_amdgcn_readfirstlane(rowptr[n + 1]);
    float acc0 = 0.f, acc1 = 0.f, acc2 = 0.f, acc3 = 0.f;
    for (int k = beg; k < end; k += 64) {
      int myidx = (k + lane < end) ? csr_src[k + lane] : 0;
      int cnt = end - k; if (cnt > 64) cnt = 64;
      int i = 0;
      for (; i + 3 < cnt; i += 4) {
        int i0 = __shfl(myidx, i);
        int i1 = __shfl(myidx, i + 1);
        int i2 = __shfl(myidx, i + 2);
        int i3 = __shfl(myidx, i + 3);
        float v0 = h[(size_t)i0 * D + lane];
        float v1 = h[(size_t)i1 * D + lane];
        float v2 = h[(size_t)i2 * D + lane];
        float v3 = h[(size_t)i3 * D + lane];
        if constexpr (APPLY) {
          v0 = elu_apply(v0, sc, sh); v1 = elu_apply(v1, sc, sh);
          v2 = elu_apply(v2, sc, sh); v3 = elu_apply(v3, sc, sh);
        }
        acc0 += v0; acc1 += v1; acc2 += v2; acc3 += v3;
      }
      for (; i < cnt; ++i) {
        int i0 = __shfl(myidx, i);
        float v0 = h[(size_t)i0 * D + lane];
        if constexpr (APPLY) v0 = elu_apply(v0, sc, sh);
        acc0 += v0;
      }
    }
    agg[(size_t)n * D + lane] = (acc0 + acc1) + (acc2 + acc3);
  }
}

// ------- two-phase LDS-staged fused matmul (34 KB LDS: As + Ws + red) -------
// phase 1: Ws=W1, As=A (+SUMAB: A+eluB);  acc = As @ Ws
// (SCALEA applied to acc between phases)
// phase 2 (DUAL): Ws=W2, As=eluB;        acc += As @ Ws
// epilogue: + bias*(MASKB? deg>0:1), RELU, store, STATS col sums.
template <int DUAL, int SUMAB, int SCALEA, int MASKB, int RELU, int STATS, int APPLYB>
__global__ void mm_kernel(const float* __restrict__ A, const float* __restrict__ Bm,
                          const float* __restrict__ W1, const float* __restrict__ W2,
                          const float* __restrict__ bias, const float* __restrict__ deg,
                          const float* __restrict__ coefB,
                          float* __restrict__ out, float* __restrict__ stats, int N) {
  __shared__ float As[64 * 64];
  __shared__ float Ws[64 * 64];
  __shared__ float red[2][256];
  int t = threadIdx.x;
  int j = t & 63;
  int g = t >> 6;
  int tile0 = blockIdx.x * 64;
  int r0 = g * 16;

  // ---- phase 1 stage ----
#pragma unroll
  for (int p = 0; p < 4; ++p) {
    int idx = t + p * 256;  // float4 slot
    *(float4*)(Ws + idx * 4) = ((const float4*)W1)[idx];
    int row = idx >> 4;
    int c4 = idx & 15;
    int rg = tile0 + row;
    float4 av = make_float4(0.f, 0.f, 0.f, 0.f);
    if (rg < N) av = *(const float4*)(A + (size_t)rg * D + c4 * 4);
    if constexpr (SUMAB) {
      float4 bv = make_float4(0.f, 0.f, 0.f, 0.f);
      if (rg < N) bv = *(const float4*)(Bm + (size_t)rg * D + c4 * 4);
      if constexpr (APPLYB) {
        float4 sc4 = *(const float4*)(coefB + c4 * 4);
        float4 sh4 = *(const float4*)(coefB + D + c4 * 4);
        bv.x = elu_apply(bv.x, sc4.x, sh4.x);
        bv.y = elu_apply(bv.y, sc4.y, sh4.y);
        bv.z = elu_apply(bv.z, sc4.z, sh4.z);
        bv.w = elu_apply(bv.w, sc4.w, sh4.w);
      }
      av.x += bv.x; av.y += bv.y; av.z += bv.z; av.w += bv.w;
    }
    *(float4*)(As + idx * 4) = av;
  }
  __syncthreads();

  float acc[16];
#pragma unroll
  for (int r = 0; r < 16; ++r) acc[r] = 0.f;

#pragma unroll
  for (int k4 = 0; k4 < 16; ++k4) {
    float w0 = Ws[(4 * k4 + 0) * 64 + j];
    float w1 = Ws[(4 * k4 + 1) * 64 + j];
    float w2 = Ws[(4 * k4 + 2) * 64 + j];
    float w3 = Ws[(4 * k4 + 3) * 64 + j];
#pragma unroll
    for (int r = 0; r < 16; ++r) {
      float4 av = *(const float4*)(As + (r0 + r) * 64 + 4 * k4);  // wave-uniform broadcast
      acc[r] += av.x * w0 + av.y * w1 + av.z * w2 + av.w * w3;
    }
  }

  if constexpr (SCALEA) {
#pragma unroll
    for (int r = 0; r < 16; ++r) {
      int rg = tile0 + r0 + r;
      acc[r] *= 1.0f / fmaxf(deg[rg < N ? rg : 0], 1.0f);
    }
  }

  if constexpr (DUAL) {
    __syncthreads();  // all phase-1 reads done before restage
#pragma unroll
    for (int p = 0; p < 4; ++p) {
      int idx = t + p * 256;
      *(float4*)(Ws + idx * 4) = ((const float4*)W2)[idx];
      int row = idx >> 4;
      int c4 = idx & 15;
      int rg = tile0 + row;
      float4 bv = make_float4(0.f, 0.f, 0.f, 0.f);
      if (rg < N) bv = *(const float4*)(Bm + (size_t)rg * D + c4 * 4);
      if constexpr (APPLYB) {
        float4 sc4 = *(const float4*)(coefB + c4 * 4);
        float4 sh4 = *(const float4*)(coefB + D + c4 * 4);
        bv.x = elu_apply(bv.x, sc4.x, sh4.x);
        bv.y = elu_apply(bv.y, sc4.y, sh4.y);
        bv.z = elu_apply(bv.z, sc4.z, sh4.z);
        bv.w = elu_apply(bv.w, sc4.w, sh4.w);
      }
      *(float4*)(As + idx * 4) = bv;
    }
    __syncthreads();
#pragma unroll
    for (int k4 = 0; k4 < 16; ++k4) {
      float w0 = Ws[(4 * k4 + 0) * 64 + j];
      float w1 = Ws[(4 * k4 + 1) * 64 + j];
      float w2 = Ws[(4 * k4 + 2) * 64 + j];
      float w3 = Ws[(4 * k4 + 3) * 64 + j];
#pragma unroll
      for (int r = 0; r < 16; ++r) {
        float4 bv = *(const float4*)(As + (r0 + r) * 64 + 4 * k4);
        acc[r] += bv.x * w0 + bv.y * w1 + bv.z * w2 + bv.w * w3;
      }
    }
  }

  float bj = bias[j];
  float s1 = 0.f, s2 = 0.f;
#pragma unroll
  for (int r = 0; r < 16; ++r) {
    int rg = tile0 + r0 + r;
    float v = acc[r];
    float bmask = 1.f;
    if constexpr (MASKB) bmask = (deg[rg < N ? rg : 0] > 0.f) ? 1.f : 0.f;
    v += bj * bmask;
    if constexpr (RELU) v = fmaxf(v, 0.f);
    if (rg < N) {
      out[(size_t)rg * D + j] = v;
      if constexpr (STATS) { s1 += v; s2 += v * v; }
    }
  }

  if constexpr (STATS) {
    red[0][t] = s1;
    red[1][t] = s2;
    __syncthreads();
    if (t < 64) {
      float t1 = red[0][t] + red[0][t + 64] + red[0][t + 128] + red[0][t + 192];
      float t2 = red[1][t] + red[1][t + 64] + red[1][t + 128] + red[1][t + 192];
      atomicAdd(&stats[t], t1);
      atomicAdd(&stats[D + t], t2);
    }
  }
}

// ---------------- BN coef ----------------
__global__ void bn_coef_kernel(const float* __restrict__ stats, const float* __restrict__ gamma,
                               const float* __restrict__ beta, float* __restrict__ coef,
                               float invN) {
  int j = threadIdx.x;
  if (j < D) {
    float mu = stats[j] * invN;
    float var = fmaxf(stats[D + j] * invN - mu * mu, 0.f);
    float rs = rsqrtf(var + 1e-5f);
    float sc = gamma[j] * rs;
    coef[j] = sc;
    coef[D + j] = beta[j] - mu * sc;
  }
}

// ---------------- global mean pool (fused BN+ELU) ----------------
template <int APPLY>
__global__ void pool_kernel(const float* __restrict__ h, const float* __restrict__ coef,
                            const int* __restrict__ batch, float* __restrict__ pooled,
                            float* __restrict__ pcnt, int N) {
  int lane = threadIdx.x & 63;
  int wid = (blockIdx.x * blockDim.x + threadIdx.x) >> 6;
  int nw = (gridDim.x * blockDim.x) >> 6;
  float sc = 1.f, sh = 0.f;
  if constexpr (APPLY) { sc = coef[lane]; sh = coef[D + lane]; }
  for (int n = wid; n < N; n += nw) {
    int b = batch[n];
    float v = h[(size_t)n * D + lane];
    if constexpr (APPLY) v = elu_apply(v, sc, sh);
    atomicAdd(&pooled[(size_t)b * D + lane], v);
    if (lane == 0) atomicAdd(&pcnt[b], 1.0f);
  }
}

// ---------------- head ----------------
__global__ void head_kernel(const float* __restrict__ pooled, const float* __restrict__ pcnt,
                            const float* __restrict__ Wout, const float* __restrict__ bout,
                            float* __restrict__ outp, int G) {
  int idx = blockIdx.x * blockDim.x + threadIdx.x;
  if (idx >= G * 16) return;
  int g = idx >> 4;
  int o = idx & 15;
  float inv = 1.0f / fmaxf(pcnt[g], 1.0f);
  float acc = 0.f;
#pragma unroll
  for (int i = 0; i < D; ++i) acc += pooled[(size_t)g * D + i] * Wout[i * 16 + o];
  outp[idx] = acc * inv + bout[o];
}

extern "C" void kernel_launch(void* const* d_in, const int* in_sizes, int n_in,
                              void* d_out, int out_size, void* d_ws, size_t ws_size,
                              hipStream_t stream) {
  (void)n_in; (void)ws_size;
  const float* x      = (const float*)d_in[0];
  const int*   edge   = (const int*)d_in[1];
  const int*   batch  = (const int*)d_in[2];
  const float* W0     = (const float*)d_in[3];
  const float* b0     = (const float*)d_in[4];
  const float* Wl     = (const float*)d_in[5];
  const float* bl     = (const float*)d_in[6];
  const float* Wr     = (const float*)d_in[7];
  const float* W2a    = (const float*)d_in[8];
  const float* b2a    = (const float*)d_in[9];
  const float* W2b    = (const float*)d_in[10];
  const float* b2b    = (const float*)d_in[11];
  const float* Wrel   = (const float*)d_in[12];
  const float* brel   = (const float*)d_in[13];
  const float* Wroot  = (const float*)d_in[14];
  const float* gammas = (const float*)d_in[15];
  const float* betas  = (const float*)d_in[16];
  const float* Wout   = (const float*)d_in[17];
  const float* bout   = (const float*)d_in[18];
  float* out = (float*)d_out;

  int N = in_sizes[0] / D;
  int E = in_sizes[1] / 2;
  int G = out_size / 16;
  const int* src = edge;
  const int* dst = edge + E;

  float* ws = (float*)d_ws;
  float* bufB = ws;                          // agg / GIN z
  float* bufP = bufB + (size_t)N * D;        // h_pre ping
  float* bufQ = bufP + (size_t)N * D;        // h_pre pong
  float* deg  = bufQ + (size_t)N * D;        // N floats
  float* stats = deg + N;                    // 128
  float* coef  = stats + 2 * D;              // 4 layers x 128
  float* pooled = coef + 4 * 2 * D;          // G*64
  float* pcnt   = pooled + (size_t)G * D;    // G
  int* hist    = (int*)(pcnt + G);           // N ints (also cursor)
  int* rowptr  = hist + N;                   // N+1 ints
  int* csr_src = rowptr + N + 1;             // E ints
  int* blocksum = csr_src + E;               // 256 ints
  int* blockoff = blocksum + NB_SCAN;        // 256 ints

  int tiles = (N + 63) / 64;
  int gather_blocks = (N * 64 + 255) / 256;
  if (gather_blocks > 8192) gather_blocks = 8192;

  // ---- build CSR ----
  hipMemsetAsync(hist, 0, N * sizeof(int), stream);
  hist_kernel<<<1024, 256, 0, stream>>>(dst, hist, E);
  scanA_kernel<<<NB_SCAN, 256, 0, stream>>>(hist, blocksum, N);
  scanB_kernel<<<1, NB_SCAN, 0, stream>>>(blocksum, blockoff, rowptr + N);
  scanC_kernel<<<NB_SCAN, 256, 0, stream>>>(hist, blockoff, rowptr, deg, N);
  hipMemsetAsync(hist, 0, N * sizeof(int), stream);
  fill_kernel<<<1024, 256, 0, stream>>>(src, dst, rowptr, hist, csr_src, E);

  // ---- layer 0: custom_mp ----
  gather_kernel<0><<<gather_blocks, 256, 0, stream>>>(x, nullptr, rowptr, csr_src, bufB, N);
  hipMemsetAsync(stats, 0, 2 * D * sizeof(float), stream);
  mm_kernel<0, 0, 1, 1, 0, 1, 0><<<tiles, 256, 0, stream>>>(
      bufB, nullptr, W0, nullptr, b0, deg, nullptr, bufP, stats, N);
  bn_coef_kernel<<<1, 64, 0, stream>>>(stats, gammas + 0 * D, betas + 0 * D, coef + 0 * 128, 1.0f / N);

  // ---- layer 1: SAGE ----
  gather_kernel<1><<<gather_blocks, 256, 0, stream>>>(bufP, coef + 0 * 128, rowptr, csr_src, bufB, N);
  hipMemsetAsync(stats, 0, 2 * D * sizeof(float), stream);
  mm_kernel<1, 0, 1, 0, 0, 1, 1><<<tiles, 256, 0, stream>>>(
      bufB, bufP, Wl, Wr, bl, deg, coef + 0 * 128, bufQ, stats, N);
  bn_coef_kernel<<<1, 64, 0, stream>>>(stats, gammas + 1 * D, betas + 1 * D, coef + 1 * 128, 1.0f / N);

  // ---- layer 2: GIN ----
  gather_kernel<1><<<gather_blocks, 256, 0, stream>>>(bufQ, coef + 1 * 128, rowptr, csr_src, bufB, N);
  mm_kernel<0, 1, 0, 0, 1, 0, 1><<<tiles, 256, 0, stream>>>(
      bufB, bufQ, W2a, nullptr, b2a, nullptr, coef + 1 * 128, bufB, nullptr, N);
  hipMemsetAsync(stats, 0, 2 * D * sizeof(float), stream);
  mm_kernel<0, 0, 0, 0, 0, 1, 0><<<tiles, 256, 0, stream>>>(
      bufB, nullptr, W2b, nullptr, b2b, nullptr, nullptr, bufP, stats, N);
  bn_coef_kernel<<<1, 64, 0, stream>>>(stats, gammas + 2 * D, betas + 2 * D, coef + 2 * 128, 1.0f / N);

  // ---- layer 3: GraphConv ----
  gather_kernel<1><<<gather_blocks, 256, 0, stream>>>(bufP, coef + 2 * 128, rowptr, csr_src, bufB, N);
  hipMemsetAsync(stats, 0, 2 * D * sizeof(float), stream);
  mm_kernel<1, 0, 0, 0, 0, 1, 1><<<tiles, 256, 0, stream>>>(
      bufB, bufP, Wrel, Wroot, brel, nullptr, coef + 2 * 128, bufQ, stats, N);
  bn_coef_kernel<<<1, 64, 0, stream>>>(stats, gammas + 3 * D, betas + 3 * D, coef + 3 * 128, 1.0f / N);

  // ---- pool + head ----
  hipMemsetAsync(pooled, 0, (size_t)G * D * sizeof(float), stream);
  hipMemsetAsync(pcnt, 0, G * sizeof(float), stream);
  pool_kernel<1><<<1024, 256, 0, stream>>>(bufQ, coef + 3 * 128, batch, pooled, pcnt, N);
  head_kernel<<<(G * 16 + 255) / 256, 256, 0, stream>>>(pooled, pcnt, Wout, bout, out, G);
}

// Round 7
// 6378.374 us; speedup vs baseline: 1.0182x; 1.0182x over previous
//
#include <hip/hip_runtime.h>
#include <math.h>

#define D 64
#define NB_SCAN 256

#define ROWS16(M) M(0, a0) M(1, a1) M(2, a2) M(3, a3) M(4, a4) M(5, a5) M(6, a6) M(7, a7) \
                  M(8, a8) M(9, a9) M(10, a10) M(11, a11) M(12, a12) M(13, a13) M(14, a14) M(15, a15)

__device__ __forceinline__ float elu_apply(float v, float sc, float sh) {
  v = v * sc + sh;
  return v > 0.f ? v : __expf(v) - 1.f;
}

// ---------------- degree histogram (int) ----------------
__global__ void hist_kernel(const int* __restrict__ dst, int* __restrict__ hist, int E) {
  int i = blockIdx.x * blockDim.x + threadIdx.x;
  int stride = gridDim.x * blockDim.x;
  for (int e = i; e < E; e += stride) atomicAdd(&hist[dst[e]], 1);
}

// ---------------- 3-pass scan ----------------
__global__ void scanA_kernel(const int* __restrict__ hist, int* __restrict__ blocksum, int N) {
  __shared__ int red[256];
  int b = blockIdx.x, t = threadIdx.x;
  int chunk = (N + NB_SCAN - 1) / NB_SCAN;
  int beg = b * chunk;
  int end = min(beg + chunk, N);
  int s = 0;
  for (int i = beg + t; i < end; i += 256) s += hist[i];
  red[t] = s;
  __syncthreads();
  for (int off = 128; off > 0; off >>= 1) {
    if (t < off) red[t] += red[t + off];
    __syncthreads();
  }
  if (t == 0) blocksum[b] = red[0];
}

__global__ void scanB_kernel(const int* __restrict__ blocksum, int* __restrict__ blockoff,
                             int* __restrict__ rowptr_last) {
  __shared__ int sm[NB_SCAN];
  int t = threadIdx.x;
  sm[t] = blocksum[t];
  __syncthreads();
  for (int off = 1; off < NB_SCAN; off <<= 1) {
    int v = (t >= off) ? sm[t - off] : 0;
    __syncthreads();
    sm[t] += v;
    __syncthreads();
  }
  blockoff[t] = (t == 0) ? 0 : sm[t - 1];
  if (t == NB_SCAN - 1) rowptr_last[0] = sm[t];
}

__global__ void scanC_kernel(const int* __restrict__ hist, const int* __restrict__ blockoff,
                             int* __restrict__ rowptr, float* __restrict__ degf, int N) {
  __shared__ int sm[256];
  int b = blockIdx.x, t = threadIdx.x;
  int chunk = (N + NB_SCAN - 1) / NB_SCAN;
  int beg = b * chunk;
  int end = min(beg + chunk, N);
  int sub = (chunk + 255) / 256;
  int mybeg = beg + t * sub;
  int myend = min(mybeg + sub, end);
  int s = 0;
  for (int i = mybeg; i < myend; ++i) s += hist[i];
  sm[t] = s;
  __syncthreads();
  for (int off = 1; off < 256; off <<= 1) {
    int v = (t >= off) ? sm[t - off] : 0;
    __syncthreads();
    sm[t] += v;
    __syncthreads();
  }
  int run = blockoff[b] + ((t == 0) ? 0 : sm[t - 1]);
  for (int i = mybeg; i < myend; ++i) {
    int h = hist[i];
    rowptr[i] = run;
    degf[i] = (float)h;
    run += h;
  }
}

// ---------------- CSR fill ----------------
__global__ void fill_kernel(const int* __restrict__ src, const int* __restrict__ dst,
                            const int* __restrict__ rowptr, int* __restrict__ cursor,
                            int* __restrict__ csr_src, int E) {
  int i = blockIdx.x * blockDim.x + threadIdx.x;
  int stride = gridDim.x * blockDim.x;
  for (int e = i; e < E; e += stride) {
    int d = dst[e];
    int pos = atomicAdd(&cursor[d], 1);
    csr_src[rowptr[d] + pos] = src[e];
  }
}

// ------- gather-sum with optional fused BN+ELU on gathered rows -------
template <int APPLY>
__global__ void gather_kernel(const float* __restrict__ h, const float* __restrict__ coef,
                              const int* __restrict__ rowptr, const int* __restrict__ csr_src,
                              float* __restrict__ agg, int N) {
  int lane = threadIdx.x & 63;
  int wid = (blockIdx.x * blockDim.x + threadIdx.x) >> 6;
  int nw = (gridDim.x * blockDim.x) >> 6;
  float sc = 1.f, sh = 0.f;
  if constexpr (APPLY) { sc = coef[lane]; sh = coef[D + lane]; }
  for (int n = wid; n < N; n += nw) {
    int beg = __builtin_amdgcn_readfirstlane(rowptr[n]);
    int end = __builtin_amdgcn_readfirstlane(rowptr[n + 1]);
    float acc0 = 0.f, acc1 = 0.f, acc2 = 0.f, acc3 = 0.f;
    for (int k = beg; k < end; k += 64) {
      int myidx = (k + lane < end) ? csr_src[k + lane] : 0;
      int cnt = end - k; if (cnt > 64) cnt = 64;
      int i = 0;
      for (; i + 3 < cnt; i += 4) {
        int i0 = __shfl(myidx, i);
        int i1 = __shfl(myidx, i + 1);
        int i2 = __shfl(myidx, i + 2);
        int i3 = __shfl(myidx, i + 3);
        float v0 = h[(size_t)i0 * D + lane];
        float v1 = h[(size_t)i1 * D + lane];
        float v2 = h[(size_t)i2 * D + lane];
        float v3 = h[(size_t)i3 * D + lane];
        if constexpr (APPLY) {
          v0 = elu_apply(v0, sc, sh); v1 = elu_apply(v1, sc, sh);
          v2 = elu_apply(v2, sc, sh); v3 = elu_apply(v3, sc, sh);
        }
        acc0 += v0; acc1 += v1; acc2 += v2; acc3 += v3;
      }
      for (; i < cnt; ++i) {
        int i0 = __shfl(myidx, i);
        float v0 = h[(size_t)i0 * D + lane];
        if constexpr (APPLY) v0 = elu_apply(v0, sc, sh);
        acc0 += v0;
      }
    }
    agg[(size_t)n * D + lane] = (acc0 + acc1) + (acc2 + acc3);
  }
}

// ------- two-phase LDS-staged fused matmul, 16 NAMED accumulators -------
// phase 1: Ws=W1, As=A (+SUMAB: A+eluB);  acc = As @ Ws
// (SCALEA applied to acc between phases)
// phase 2 (DUAL): Ws=W2, As=eluB;        acc += As @ Ws
// epilogue: + bias*(MASKB? deg>0:1), RELU, store, STATS col sums.
template <int DUAL, int SUMAB, int SCALEA, int MASKB, int RELU, int STATS, int APPLYB>
__global__ __launch_bounds__(256, 4)
void mm_kernel(const float* __restrict__ A, const float* __restrict__ Bm,
               const float* __restrict__ W1, const float* __restrict__ W2,
               const float* __restrict__ bias, const float* __restrict__ deg,
               const float* __restrict__ coefB,
               float* __restrict__ out, float* __restrict__ stats, int N) {
  __shared__ float As[64 * 64];
  __shared__ float Ws[64 * 64];
  __shared__ float red[2][256];
  int t = threadIdx.x;
  int j = t & 63;
  int g = t >> 6;
  int tile0 = blockIdx.x * 64;
  int r0 = g * 16;

  // ---- phase 1 stage ----
#pragma unroll
  for (int p = 0; p < 4; ++p) {
    int idx = t + p * 256;  // float4 slot
    *(float4*)(Ws + idx * 4) = ((const float4*)W1)[idx];
    int row = idx >> 4;
    int c4 = idx & 15;
    int rg = tile0 + row;
    float4 av = make_float4(0.f, 0.f, 0.f, 0.f);
    if (rg < N) av = *(const float4*)(A + (size_t)rg * D + c4 * 4);
    if constexpr (SUMAB) {
      float4 bv = make_float4(0.f, 0.f, 0.f, 0.f);
      if (rg < N) bv = *(const float4*)(Bm + (size_t)rg * D + c4 * 4);
      if constexpr (APPLYB) {
        float4 sc4 = *(const float4*)(coefB + c4 * 4);
        float4 sh4 = *(const float4*)(coefB + D + c4 * 4);
        bv.x = elu_apply(bv.x, sc4.x, sh4.x);
        bv.y = elu_apply(bv.y, sc4.y, sh4.y);
        bv.z = elu_apply(bv.z, sc4.z, sh4.z);
        bv.w = elu_apply(bv.w, sc4.w, sh4.w);
      }
      av.x += bv.x; av.y += bv.y; av.z += bv.z; av.w += bv.w;
    }
    *(float4*)(As + idx * 4) = av;
  }
  __syncthreads();

  float a0 = 0.f, a1 = 0.f, a2 = 0.f, a3 = 0.f, a4 = 0.f, a5 = 0.f, a6 = 0.f, a7 = 0.f;
  float a8 = 0.f, a9 = 0.f, a10 = 0.f, a11 = 0.f, a12 = 0.f, a13 = 0.f, a14 = 0.f, a15 = 0.f;

#define MM_FMA(rr, accv) { float4 av = *(const float4*)(As + (r0 + rr) * 64 + 4 * k4); \
                           accv += av.x * w0 + av.y * w1 + av.z * w2 + av.w * w3; }

#pragma unroll
  for (int k4 = 0; k4 < 16; ++k4) {
    float w0 = Ws[(4 * k4 + 0) * 64 + j];
    float w1 = Ws[(4 * k4 + 1) * 64 + j];
    float w2 = Ws[(4 * k4 + 2) * 64 + j];
    float w3 = Ws[(4 * k4 + 3) * 64 + j];
    ROWS16(MM_FMA)
  }

  if constexpr (SCALEA) {
#define MM_SCALE(rr, accv) { int rg = tile0 + r0 + rr; \
                             accv *= 1.0f / fmaxf(deg[rg < N ? rg : 0], 1.0f); }
    ROWS16(MM_SCALE)
#undef MM_SCALE
  }

  if constexpr (DUAL) {
    __syncthreads();  // all phase-1 reads done before restage
#pragma unroll
    for (int p = 0; p < 4; ++p) {
      int idx = t + p * 256;
      *(float4*)(Ws + idx * 4) = ((const float4*)W2)[idx];
      int row = idx >> 4;
      int c4 = idx & 15;
      int rg = tile0 + row;
      float4 bv = make_float4(0.f, 0.f, 0.f, 0.f);
      if (rg < N) bv = *(const float4*)(Bm + (size_t)rg * D + c4 * 4);
      if constexpr (APPLYB) {
        float4 sc4 = *(const float4*)(coefB + c4 * 4);
        float4 sh4 = *(const float4*)(coefB + D + c4 * 4);
        bv.x = elu_apply(bv.x, sc4.x, sh4.x);
        bv.y = elu_apply(bv.y, sc4.y, sh4.y);
        bv.z = elu_apply(bv.z, sc4.z, sh4.z);
        bv.w = elu_apply(bv.w, sc4.w, sh4.w);
      }
      *(float4*)(As + idx * 4) = bv;
    }
    __syncthreads();
#pragma unroll
    for (int k4 = 0; k4 < 16; ++k4) {
      float w0 = Ws[(4 * k4 + 0) * 64 + j];
      float w1 = Ws[(4 * k4 + 1) * 64 + j];
      float w2 = Ws[(4 * k4 + 2) * 64 + j];
      float w3 = Ws[(4 * k4 + 3) * 64 + j];
      ROWS16(MM_FMA)
    }
  }
#undef MM_FMA

  float bj = bias[j];
  float s1 = 0.f, s2 = 0.f;
#define MM_EPI(rr, accv) { int rg = tile0 + r0 + rr; float v = accv; \
    float bmask = 1.f; \
    if constexpr (MASKB) bmask = (deg[rg < N ? rg : 0] > 0.f) ? 1.f : 0.f; \
    v += bj * bmask; \
    if constexpr (RELU) v = fmaxf(v, 0.f); \
    if (rg < N) { out[(size_t)rg * D + j] = v; \
      if constexpr (STATS) { s1 += v; s2 += v * v; } } }
  ROWS16(MM_EPI)
#undef MM_EPI

  if constexpr (STATS) {
    red[0][t] = s1;
    red[1][t] = s2;
    __syncthreads();
    if (t < 64) {
      float t1 = red[0][t] + red[0][t + 64] + red[0][t + 128] + red[0][t + 192];
      float t2 = red[1][t] + red[1][t + 64] + red[1][t + 128] + red[1][t + 192];
      atomicAdd(&stats[t], t1);
      atomicAdd(&stats[D + t], t2);
    }
  }
}

// ---------------- BN coef ----------------
__global__ void bn_coef_kernel(const float* __restrict__ stats, const float* __restrict__ gamma,
                               const float* __restrict__ beta, float* __restrict__ coef,
                               float invN) {
  int j = threadIdx.x;
  if (j < D) {
    float mu = stats[j] * invN;
    float var = fmaxf(stats[D + j] * invN - mu * mu, 0.f);
    float rs = rsqrtf(var + 1e-5f);
    float sc = gamma[j] * rs;
    coef[j] = sc;
    coef[D + j] = beta[j] - mu * sc;
  }
}

// ---------------- global mean pool (fused BN+ELU) ----------------
template <int APPLY>
__global__ void pool_kernel(const float* __restrict__ h, const float* __restrict__ coef,
                            const int* __restrict__ batch, float* __restrict__ pooled,
                            float* __restrict__ pcnt, int N) {
  int lane = threadIdx.x & 63;
  int wid = (blockIdx.x * blockDim.x + threadIdx.x) >> 6;
  int nw = (gridDim.x * blockDim.x) >> 6;
  float sc = 1.f, sh = 0.f;
  if constexpr (APPLY) { sc = coef[lane]; sh = coef[D + lane]; }
  for (int n = wid; n < N; n += nw) {
    int b = batch[n];
    float v = h[(size_t)n * D + lane];
    if constexpr (APPLY) v = elu_apply(v, sc, sh);
    atomicAdd(&pooled[(size_t)b * D + lane], v);
    if (lane == 0) atomicAdd(&pcnt[b], 1.0f);
  }
}

// ---------------- head ----------------
__global__ void head_kernel(const float* __restrict__ pooled, const float* __restrict__ pcnt,
                            const float* __restrict__ Wout, const float* __restrict__ bout,
                            float* __restrict__ outp, int G) {
  int idx = blockIdx.x * blockDim.x + threadIdx.x;
  if (idx >= G * 16) return;
  int g = idx >> 4;
  int o = idx & 15;
  float inv = 1.0f / fmaxf(pcnt[g], 1.0f);
  float acc = 0.f;
#pragma unroll
  for (int i = 0; i < D; ++i) acc += pooled[(size_t)g * D + i] * Wout[i * 16 + o];
  outp[idx] = acc * inv + bout[o];
}

extern "C" void kernel_launch(void* const* d_in, const int* in_sizes, int n_in,
                              void* d_out, int out_size, void* d_ws, size_t ws_size,
                              hipStream_t stream) {
  (void)n_in; (void)ws_size;
  const float* x      = (const float*)d_in[0];
  const int*   edge   = (const int*)d_in[1];
  const int*   batch  = (const int*)d_in[2];
  const float* W0     = (const float*)d_in[3];
  const float* b0     = (const float*)d_in[4];
  const float* Wl     = (const float*)d_in[5];
  const float* bl     = (const float*)d_in[6];
  const float* Wr     = (const float*)d_in[7];
  const float* W2a    = (const float*)d_in[8];
  const float* b2a    = (const float*)d_in[9];
  const float* W2b    = (const float*)d_in[10];
  const float* b2b    = (const float*)d_in[11];
  const float* Wrel   = (const float*)d_in[12];
  const float* brel   = (const float*)d_in[13];
  const float* Wroot  = (const float*)d_in[14];
  const float* gammas = (const float*)d_in[15];
  const float* betas  = (const float*)d_in[16];
  const float* Wout   = (const float*)d_in[17];
  const float* bout   = (const float*)d_in[18];
  float* out = (float*)d_out;

  int N = in_sizes[0] / D;
  int E = in_sizes[1] / 2;
  int G = out_size / 16;
  const int* src = edge;
  const int* dst = edge + E;

  float* ws = (float*)d_ws;
  float* bufB = ws;                          // agg / GIN z
  float* bufP = bufB + (size_t)N * D;        // h_pre ping
  float* bufQ = bufP + (size_t)N * D;        // h_pre pong
  float* deg  = bufQ + (size_t)N * D;        // N floats
  float* stats = deg + N;                    // 128
  float* coef  = stats + 2 * D;              // 4 layers x 128
  float* pooled = coef + 4 * 2 * D;          // G*64
  float* pcnt   = pooled + (size_t)G * D;    // G
  int* hist    = (int*)(pcnt + G);           // N ints (also cursor)
  int* rowptr  = hist + N;                   // N+1 ints
  int* csr_src = rowptr + N + 1;             // E ints
  int* blocksum = csr_src + E;               // 256 ints
  int* blockoff = blocksum + NB_SCAN;        // 256 ints

  int tiles = (N + 63) / 64;
  int gather_blocks = (N * 64 + 255) / 256;
  if (gather_blocks > 8192) gather_blocks = 8192;

  // ---- build CSR ----
  hipMemsetAsync(hist, 0, N * sizeof(int), stream);
  hist_kernel<<<1024, 256, 0, stream>>>(dst, hist, E);
  scanA_kernel<<<NB_SCAN, 256, 0, stream>>>(hist, blocksum, N);
  scanB_kernel<<<1, NB_SCAN, 0, stream>>>(blocksum, blockoff, rowptr + N);
  scanC_kernel<<<NB_SCAN, 256, 0, stream>>>(hist, blockoff, rowptr, deg, N);
  hipMemsetAsync(hist, 0, N * sizeof(int), stream);
  fill_kernel<<<1024, 256, 0, stream>>>(src, dst, rowptr, hist, csr_src, E);

  // ---- layer 0: custom_mp ----
  gather_kernel<0><<<gather_blocks, 256, 0, stream>>>(x, nullptr, rowptr, csr_src, bufB, N);
  hipMemsetAsync(stats, 0, 2 * D * sizeof(float), stream);
  mm_kernel<0, 0, 1, 1, 0, 1, 0><<<tiles, 256, 0, stream>>>(
      bufB, nullptr, W0, nullptr, b0, deg, nullptr, bufP, stats, N);
  bn_coef_kernel<<<1, 64, 0, stream>>>(stats, gammas + 0 * D, betas + 0 * D, coef + 0 * 128, 1.0f / N);

  // ---- layer 1: SAGE ----
  gather_kernel<1><<<gather_blocks, 256, 0, stream>>>(bufP, coef + 0 * 128, rowptr, csr_src, bufB, N);
  hipMemsetAsync(stats, 0, 2 * D * sizeof(float), stream);
  mm_kernel<1, 0, 1, 0, 0, 1, 1><<<tiles, 256, 0, stream>>>(
      bufB, bufP, Wl, Wr, bl, deg, coef + 0 * 128, bufQ, stats, N);
  bn_coef_kernel<<<1, 64, 0, stream>>>(stats, gammas + 1 * D, betas + 1 * D, coef + 1 * 128, 1.0f / N);

  // ---- layer 2: GIN ----
  gather_kernel<1><<<gather_blocks, 256, 0, stream>>>(bufQ, coef + 1 * 128, rowptr, csr_src, bufB, N);
  mm_kernel<0, 1, 0, 0, 1, 0, 1><<<tiles, 256, 0, stream>>>(
      bufB, bufQ, W2a, nullptr, b2a, nullptr, coef + 1 * 128, bufB, nullptr, N);
  hipMemsetAsync(stats, 0, 2 * D * sizeof(float), stream);
  mm_kernel<0, 0, 0, 0, 0, 1, 0><<<tiles, 256, 0, stream>>>(
      bufB, nullptr, W2b, nullptr, b2b, nullptr, nullptr, bufP, stats, N);
  bn_coef_kernel<<<1, 64, 0, stream>>>(stats, gammas + 2 * D, betas + 2 * D, coef + 2 * 128, 1.0f / N);

  // ---- layer 3: GraphConv ----
  gather_kernel<1><<<gather_blocks, 256, 0, stream>>>(bufP, coef + 2 * 128, rowptr, csr_src, bufB, N);
  hipMemsetAsync(stats, 0, 2 * D * sizeof(float), stream);
  mm_kernel<1, 0, 0, 0, 0, 1, 1><<<tiles, 256, 0, stream>>>(
      bufB, bufP, Wrel, Wroot, brel, nullptr, coef + 2 * 128, bufQ, stats, N);
  bn_coef_kernel<<<1, 64, 0, stream>>>(stats, gammas + 3 * D, betas + 3 * D, coef + 3 * 128, 1.0f / N);

  // ---- pool + head ----
  hipMemsetAsync(pooled, 0, (size_t)G * D * sizeof(float), stream);
  hipMemsetAsync(pcnt, 0, G * sizeof(float), stream);
  pool_kernel<1><<<1024, 256, 0, stream>>>(bufQ, coef + 3 * 128, batch, pooled, pcnt, N);
  head_kernel<<<(G * 16 + 255) / 256, 256, 0, stream>>>(pooled, pcnt, Wout, bout, out, G);
}

// Round 8
// 946.717 us; speedup vs baseline: 6.8599x; 6.7374x over previous
//
#include <hip/hip_runtime.h>
#include <math.h>

#define D 64
#define NB_SCAN 256

// ---------------- degree histogram (int) ----------------
__global__ void hist_kernel(const int* __restrict__ dst, int* __restrict__ hist, int E) {
  int i = blockIdx.x * blockDim.x + threadIdx.x;
  int stride = gridDim.x * blockDim.x;
  for (int e = i; e < E; e += stride) atomicAdd(&hist[dst[e]], 1);
}

// ---------------- 3-pass scan ----------------
__global__ void scanA_kernel(const int* __restrict__ hist, int* __restrict__ blocksum, int N) {
  __shared__ int red[256];
  int b = blockIdx.x, t = threadIdx.x;
  int chunk = (N + NB_SCAN - 1) / NB_SCAN;
  int beg = b * chunk;
  int end = min(beg + chunk, N);
  int s = 0;
  for (int i = beg + t; i < end; i += 256) s += hist[i];
  red[t] = s;
  __syncthreads();
  for (int off = 128; off > 0; off >>= 1) {
    if (t < off) red[t] += red[t + off];
    __syncthreads();
  }
  if (t == 0) blocksum[b] = red[0];
}

__global__ void scanB_kernel(const int* __restrict__ blocksum, int* __restrict__ blockoff,
                             int* __restrict__ rowptr_last) {
  __shared__ int sm[NB_SCAN];
  int t = threadIdx.x;
  sm[t] = blocksum[t];
  __syncthreads();
  for (int off = 1; off < NB_SCAN; off <<= 1) {
    int v = (t >= off) ? sm[t - off] : 0;
    __syncthreads();
    sm[t] += v;
    __syncthreads();
  }
  blockoff[t] = (t == 0) ? 0 : sm[t - 1];
  if (t == NB_SCAN - 1) rowptr_last[0] = sm[t];
}

__global__ void scanC_kernel(const int* __restrict__ hist, const int* __restrict__ blockoff,
                             int* __restrict__ rowptr, float* __restrict__ degf, int N) {
  __shared__ int sm[256];
  int b = blockIdx.x, t = threadIdx.x;
  int chunk = (N + NB_SCAN - 1) / NB_SCAN;
  int beg = b * chunk;
  int end = min(beg + chunk, N);
  int sub = (chunk + 255) / 256;
  int mybeg = beg + t * sub;
  int myend = min(mybeg + sub, end);
  int s = 0;
  for (int i = mybeg; i < myend; ++i) s += hist[i];
  sm[t] = s;
  __syncthreads();
  for (int off = 1; off < 256; off <<= 1) {
    int v = (t >= off) ? sm[t - off] : 0;
    __syncthreads();
    sm[t] += v;
    __syncthreads();
  }
  int run = blockoff[b] + ((t == 0) ? 0 : sm[t - 1]);
  for (int i = mybeg; i < myend; ++i) {
    int h = hist[i];
    rowptr[i] = run;
    degf[i] = (float)h;
    run += h;
  }
}

// ---------------- CSR fill ----------------
__global__ void fill_kernel(const int* __restrict__ src, const int* __restrict__ dst,
                            const int* __restrict__ rowptr, int* __restrict__ cursor,
                            int* __restrict__ csr_src, int E) {
  int i = blockIdx.x * blockDim.x + threadIdx.x;
  int stride = gridDim.x * blockDim.x;
  for (int e = i; e < E; e += stride) {
    int d = dst[e];
    int pos = atomicAdd(&cursor[d], 1);
    csr_src[rowptr[d] + pos] = src[e];
  }
}

// ---------------- gather-sum aggregation: agg[n] = sum_{j in nbr(n)} h[j] ----------------
__global__ void gather_kernel(const float* __restrict__ h, const int* __restrict__ rowptr,
                              const int* __restrict__ csr_src, float* __restrict__ agg, int N) {
  int lane = threadIdx.x & 63;
  int wid = (blockIdx.x * blockDim.x + threadIdx.x) >> 6;
  int nw = (gridDim.x * blockDim.x) >> 6;
  for (int n = wid; n < N; n += nw) {
    int beg = __builtin_amdgcn_readfirstlane(rowptr[n]);
    int end = __builtin_amdgcn_readfirstlane(rowptr[n + 1]);
    float acc0 = 0.f, acc1 = 0.f;
    for (int k = beg; k < end; k += 64) {
      int myidx = (k + lane < end) ? csr_src[k + lane] : 0;
      int cnt = end - k; if (cnt > 64) cnt = 64;
      int i = 0;
      for (; i + 1 < cnt; i += 2) {
        int i0 = __shfl(myidx, i);
        int i1 = __shfl(myidx, i + 1);
        acc0 += h[(size_t)i0 * D + lane];
        acc1 += h[(size_t)i1 * D + lane];
      }
      if (i < cnt) {
        int i0 = __shfl(myidx, i);
        acc0 += h[(size_t)i0 * D + lane];
      }
    }
    agg[(size_t)n * D + lane] = acc0 + acc1;
  }
}

// ---------------- fused matmul (R3 structure: per-thread weight columns, uniform row s_loads) ----------------
template <int DUAL, int SUMAB, int SCALEA, int MASKB, int RELU, int STATS>
__global__ __launch_bounds__(256, 2)
void mm_kernel(const float* __restrict__ A, const float* __restrict__ B,
               const float* __restrict__ W1, const float* __restrict__ W2,
               const float* __restrict__ bias, const float* __restrict__ deg,
               float* __restrict__ out, float* __restrict__ stats, int N) {
  int j = threadIdx.x & 63;
  int g = threadIdx.x >> 6;  // wave id within block (4 waves)

  float w1c[D];
#pragma unroll
  for (int k = 0; k < D; ++k) w1c[k] = W1[k * D + j];
  float w2c[DUAL ? D : 1];
  if constexpr (DUAL) {
#pragma unroll
    for (int k = 0; k < D; ++k) w2c[k] = W2[k * D + j];
  }
  float bj = bias[j];

  float s1 = 0.f, s2 = 0.f;

  for (int tile = blockIdx.x; tile * 64 < N; tile += gridDim.x) {
    int r0 = tile * 64 + g * 16;
    for (int r = 0; r < 16; ++r) {
      int row = __builtin_amdgcn_readfirstlane(r0 + r);
      if (row >= N) break;
      const float4* pa = (const float4*)(A + (size_t)row * D);
      float a0 = 0.f, a1 = 0.f, a2 = 0.f, a3 = 0.f;
#pragma unroll
      for (int k = 0; k < 16; ++k) {
        float4 av = pa[k];
        if constexpr (SUMAB) {
          const float4* pb = (const float4*)(B + (size_t)row * D);
          float4 bv = pb[k];
          av.x += bv.x; av.y += bv.y; av.z += bv.z; av.w += bv.w;
        }
        a0 += av.x * w1c[4 * k + 0];
        a1 += av.y * w1c[4 * k + 1];
        a2 += av.z * w1c[4 * k + 2];
        a3 += av.w * w1c[4 * k + 3];
      }
      float acc = (a0 + a1) + (a2 + a3);
      if constexpr (SCALEA) {
        float dv = deg[row];
        acc *= 1.0f / fmaxf(dv, 1.0f);
      }
      if constexpr (DUAL) {
        const float4* pb = (const float4*)(B + (size_t)row * D);
        float b0 = 0.f, b1 = 0.f, b2 = 0.f, b3 = 0.f;
#pragma unroll
        for (int k = 0; k < 16; ++k) {
          float4 bv = pb[k];
          b0 += bv.x * w2c[4 * k + 0];
          b1 += bv.y * w2c[4 * k + 1];
          b2 += bv.z * w2c[4 * k + 2];
          b3 += bv.w * w2c[4 * k + 3];
        }
        acc += (b0 + b1) + (b2 + b3);
      }
      float bmask = 1.f;
      if constexpr (MASKB) bmask = (deg[row] > 0.f) ? 1.f : 0.f;
      acc += bj * bmask;
      if constexpr (RELU) acc = fmaxf(acc, 0.f);
      out[(size_t)row * D + j] = acc;
      if constexpr (STATS) {
        s1 += acc;
        s2 += acc * acc;
      }
    }
  }

  if constexpr (STATS) {
    __shared__ float red[2][256];
    red[0][threadIdx.x] = s1;
    red[1][threadIdx.x] = s2;
    __syncthreads();
    if (threadIdx.x < 64) {
      int t = threadIdx.x;
      float t1 = red[0][t] + red[0][t + 64] + red[0][t + 128] + red[0][t + 192];
      float t2 = red[1][t] + red[1][t + 64] + red[1][t + 128] + red[1][t + 192];
      atomicAdd(&stats[t], t1);
      atomicAdd(&stats[D + t], t2);
    }
  }
}

// ---------------- BN coef: scale/shift from sums ----------------
__global__ void bn_coef_kernel(const float* __restrict__ stats, const float* __restrict__ gamma,
                               const float* __restrict__ beta, float* __restrict__ coef,
                               float invN) {
  int j = threadIdx.x;
  if (j < D) {
    float mu = stats[j] * invN;
    float var = fmaxf(stats[D + j] * invN - mu * mu, 0.f);
    float rs = rsqrtf(var + 1e-5f);
    float sc = gamma[j] * rs;
    coef[j] = sc;
    coef[D + j] = beta[j] - mu * sc;
  }
}

// ---------------- BN apply + ELU ----------------
__global__ void apply_kernel(const float* __restrict__ hpre, const float* __restrict__ coef,
                             float* __restrict__ hout, int total4) {
  int i = blockIdx.x * blockDim.x + threadIdx.x;
  int stride = gridDim.x * blockDim.x;
  const float4* in4 = (const float4*)hpre;
  float4* out4 = (float4*)hout;
  const float4* c4 = (const float4*)coef;  // 16 scale vecs, 16 shift vecs
  for (int idx = i; idx < total4; idx += stride) {
    int col4 = idx & 15;
    float4 sc = c4[col4];
    float4 sh = c4[16 + col4];
    float4 v = in4[idx];
    float4 r;
    r.x = v.x * sc.x + sh.x;
    r.y = v.y * sc.y + sh.y;
    r.z = v.z * sc.z + sh.z;
    r.w = v.w * sc.w + sh.w;
    r.x = r.x > 0.f ? r.x : __expf(r.x) - 1.f;
    r.y = r.y > 0.f ? r.y : __expf(r.y) - 1.f;
    r.z = r.z > 0.f ? r.z : __expf(r.z) - 1.f;
    r.w = r.w > 0.f ? r.w : __expf(r.w) - 1.f;
    out4[idx] = r;
  }
}

// ---------------- global mean pool (sums + counts) ----------------
__global__ void pool_kernel(const float* __restrict__ h, const int* __restrict__ batch,
                            float* __restrict__ pooled, float* __restrict__ pcnt, int N) {
  int lane = threadIdx.x & 63;
  int wid = (blockIdx.x * blockDim.x + threadIdx.x) >> 6;
  int nw = (gridDim.x * blockDim.x) >> 6;
  for (int n = wid; n < N; n += nw) {
    int b = batch[n];
    atomicAdd(&pooled[(size_t)b * D + lane], h[(size_t)n * D + lane]);
    if (lane == 0) atomicAdd(&pcnt[b], 1.0f);
  }
}

// ---------------- head: out = (pooled/cnt) @ Wout + bout ----------------
__global__ void head_kernel(const float* __restrict__ pooled, const float* __restrict__ pcnt,
                            const float* __restrict__ Wout, const float* __restrict__ bout,
                            float* __restrict__ outp, int G) {
  int idx = blockIdx.x * blockDim.x + threadIdx.x;
  if (idx >= G * 16) return;
  int g = idx >> 4;
  int o = idx & 15;
  float inv = 1.0f / fmaxf(pcnt[g], 1.0f);
  float acc = 0.f;
#pragma unroll
  for (int i = 0; i < D; ++i) acc += pooled[(size_t)g * D + i] * Wout[i * 16 + o];
  outp[idx] = acc * inv + bout[o];
}

extern "C" void kernel_launch(void* const* d_in, const int* in_sizes, int n_in,
                              void* d_out, int out_size, void* d_ws, size_t ws_size,
                              hipStream_t stream) {
  (void)n_in; (void)ws_size;
  const float* x      = (const float*)d_in[0];
  const int*   edge   = (const int*)d_in[1];
  const int*   batch  = (const int*)d_in[2];
  const float* W0     = (const float*)d_in[3];
  const float* b0     = (const float*)d_in[4];
  const float* Wl     = (const float*)d_in[5];
  const float* bl     = (const float*)d_in[6];
  const float* Wr     = (const float*)d_in[7];
  const float* W2a    = (const float*)d_in[8];
  const float* b2a    = (const float*)d_in[9];
  const float* W2b    = (const float*)d_in[10];
  const float* b2b    = (const float*)d_in[11];
  const float* Wrel   = (const float*)d_in[12];
  const float* brel   = (const float*)d_in[13];
  const float* Wroot  = (const float*)d_in[14];
  const float* gammas = (const float*)d_in[15];
  const float* betas  = (const float*)d_in[16];
  const float* Wout   = (const float*)d_in[17];
  const float* bout   = (const float*)d_in[18];
  float* out = (float*)d_out;

  int N = in_sizes[0] / D;
  int E = in_sizes[1] / 2;
  int G = out_size / 16;
  const int* src = edge;
  const int* dst = edge + E;

  float* ws = (float*)d_ws;
  float* bufA = ws;                          // h (activations)
  float* bufB = bufA + (size_t)N * D;        // agg / s / GIN tmp
  float* bufC = bufB + (size_t)N * D;        // h_pre
  float* deg  = bufC + (size_t)N * D;        // N floats
  float* stats = deg + N;                    // 128
  float* coef  = stats + 2 * D;              // 128
  float* pooled = coef + 2 * D;              // G*64
  float* pcnt   = pooled + (size_t)G * D;    // G
  int* hist    = (int*)(pcnt + G);           // N ints (also cursor)
  int* rowptr  = hist + N;                   // N+1 ints
  int* csr_src = rowptr + N + 1;             // E ints
  int* blocksum = csr_src + E;               // 256 ints
  int* blockoff = blocksum + NB_SCAN;        // 256 ints

  int tiles = (N + 63) / 64;
  int total4 = N * D / 4;
  int gather_blocks = (N * 64 + 255) / 256;
  if (gather_blocks > 8192) gather_blocks = 8192;

  // ---- build CSR (once; reused by all 4 layers) ----
  hipMemsetAsync(hist, 0, N * sizeof(int), stream);
  hist_kernel<<<1024, 256, 0, stream>>>(dst, hist, E);
  scanA_kernel<<<NB_SCAN, 256, 0, stream>>>(hist, blocksum, N);
  scanB_kernel<<<1, NB_SCAN, 0, stream>>>(blocksum, blockoff, rowptr + N);
  scanC_kernel<<<NB_SCAN, 256, 0, stream>>>(hist, blockoff, rowptr, deg, N);
  hipMemsetAsync(hist, 0, N * sizeof(int), stream);  // reuse as cursor
  fill_kernel<<<1024, 256, 0, stream>>>(src, dst, rowptr, hist, csr_src, E);

  // ---- layer 0: custom_mp (mean agg of x, lin, masked bias) ----
  gather_kernel<<<gather_blocks, 256, 0, stream>>>(x, rowptr, csr_src, bufB, N);
  hipMemsetAsync(stats, 0, 2 * D * sizeof(float), stream);
  mm_kernel<0, 0, 1, 1, 0, 1><<<tiles, 256, 0, stream>>>(bufB, nullptr, W0, nullptr, b0, deg, bufC, stats, N);
  bn_coef_kernel<<<1, 64, 0, stream>>>(stats, gammas + 0 * D, betas + 0 * D, coef, 1.0f / N);
  apply_kernel<<<2048, 256, 0, stream>>>(bufC, coef, bufA, total4);

  // ---- layer 1: SAGE (mean agg @ Wl + bl + h @ Wr) ----
  gather_kernel<<<gather_blocks, 256, 0, stream>>>(bufA, rowptr, csr_src, bufB, N);
  hipMemsetAsync(stats, 0, 2 * D * sizeof(float), stream);
  mm_kernel<1, 0, 1, 0, 0, 1><<<tiles, 256, 0, stream>>>(bufB, bufA, Wl, Wr, bl, deg, bufC, stats, N);
  bn_coef_kernel<<<1, 64, 0, stream>>>(stats, gammas + 1 * D, betas + 1 * D, coef, 1.0f / N);
  apply_kernel<<<2048, 256, 0, stream>>>(bufC, coef, bufA, total4);

  // ---- layer 2: GIN (relu((h+s)@W2a+b2a) @ W2b + b2b) ----
  gather_kernel<<<gather_blocks, 256, 0, stream>>>(bufA, rowptr, csr_src, bufB, N);
  mm_kernel<0, 1, 0, 0, 1, 0><<<tiles, 256, 0, stream>>>(bufB, bufA, W2a, nullptr, b2a, nullptr, bufB, nullptr, N);
  hipMemsetAsync(stats, 0, 2 * D * sizeof(float), stream);
  mm_kernel<0, 0, 0, 0, 0, 1><<<tiles, 256, 0, stream>>>(bufB, nullptr, W2b, nullptr, b2b, nullptr, bufC, stats, N);
  bn_coef_kernel<<<1, 64, 0, stream>>>(stats, gammas + 2 * D, betas + 2 * D, coef, 1.0f / N);
  apply_kernel<<<2048, 256, 0, stream>>>(bufC, coef, bufA, total4);

  // ---- layer 3: GraphConv (s@Wrel + brel + h@Wroot) ----
  gather_kernel<<<gather_blocks, 256, 0, stream>>>(bufA, rowptr, csr_src, bufB, N);
  hipMemsetAsync(stats, 0, 2 * D * sizeof(float), stream);
  mm_kernel<1, 0, 0, 0, 0, 1><<<tiles, 256, 0, stream>>>(bufB, bufA, Wrel, Wroot, brel, nullptr, bufC, stats, N);
  bn_coef_kernel<<<1, 64, 0, stream>>>(stats, gammas + 3 * D, betas + 3 * D, coef, 1.0f / N);
  apply_kernel<<<2048, 256, 0, stream>>>(bufC, coef, bufA, total4);

  // ---- global mean pool + head ----
  hipMemsetAsync(pooled, 0, (size_t)G * D * sizeof(float), stream);
  hipMemsetAsync(pcnt, 0, G * sizeof(float), stream);
  pool_kernel<<<1024, 256, 0, stream>>>(bufA, batch, pooled, pcnt, N);
  head_kernel<<<(G * 16 + 255) / 256, 256, 0, stream>>>(pooled, pcnt, Wout, bout, out, G);
}

// Round 9
// 908.686 us; speedup vs baseline: 7.1470x; 1.0419x over previous
//
#include <hip/hip_runtime.h>
#include <math.h>

#define D 64
#define NB_SCAN 256

typedef unsigned short ushort_t;

__device__ __forceinline__ ushort_t f2bf(float f) {
  unsigned int u = __float_as_uint(f);
  unsigned int r = (u + 0x7fffu + ((u >> 16) & 1u)) >> 16;  // RNE
  return (ushort_t)r;
}

// ---------------- degree histogram (int) ----------------
__global__ void hist_kernel(const int* __restrict__ dst, int* __restrict__ hist, int E) {
  int i = blockIdx.x * blockDim.x + threadIdx.x;
  int stride = gridDim.x * blockDim.x;
  for (int e = i; e < E; e += stride) atomicAdd(&hist[dst[e]], 1);
}

// ---------------- 3-pass scan ----------------
__global__ void scanA_kernel(const int* __restrict__ hist, int* __restrict__ blocksum, int N) {
  __shared__ int red[256];
  int b = blockIdx.x, t = threadIdx.x;
  int chunk = (N + NB_SCAN - 1) / NB_SCAN;
  int beg = b * chunk;
  int end = min(beg + chunk, N);
  int s = 0;
  for (int i = beg + t; i < end; i += 256) s += hist[i];
  red[t] = s;
  __syncthreads();
  for (int off = 128; off > 0; off >>= 1) {
    if (t < off) red[t] += red[t + off];
    __syncthreads();
  }
  if (t == 0) blocksum[b] = red[0];
}

__global__ void scanB_kernel(const int* __restrict__ blocksum, int* __restrict__ blockoff,
                             int* __restrict__ rowptr_last) {
  __shared__ int sm[NB_SCAN];
  int t = threadIdx.x;
  sm[t] = blocksum[t];
  __syncthreads();
  for (int off = 1; off < NB_SCAN; off <<= 1) {
    int v = (t >= off) ? sm[t - off] : 0;
    __syncthreads();
    sm[t] += v;
    __syncthreads();
  }
  blockoff[t] = (t == 0) ? 0 : sm[t - 1];
  if (t == NB_SCAN - 1) rowptr_last[0] = sm[t];
}

__global__ void scanC_kernel(const int* __restrict__ hist, const int* __restrict__ blockoff,
                             int* __restrict__ rowptr, float* __restrict__ degf, int N) {
  __shared__ int sm[256];
  int b = blockIdx.x, t = threadIdx.x;
  int chunk = (N + NB_SCAN - 1) / NB_SCAN;
  int beg = b * chunk;
  int end = min(beg + chunk, N);
  int sub = (chunk + 255) / 256;
  int mybeg = beg + t * sub;
  int myend = min(mybeg + sub, end);
  int s = 0;
  for (int i = mybeg; i < myend; ++i) s += hist[i];
  sm[t] = s;
  __syncthreads();
  for (int off = 1; off < 256; off <<= 1) {
    int v = (t >= off) ? sm[t - off] : 0;
    __syncthreads();
    sm[t] += v;
    __syncthreads();
  }
  int run = blockoff[b] + ((t == 0) ? 0 : sm[t - 1]);
  for (int i = mybeg; i < myend; ++i) {
    int h = hist[i];
    rowptr[i] = run;
    degf[i] = (float)h;
    run += h;
  }
}

// ---------------- CSR fill ----------------
__global__ void fill_kernel(const int* __restrict__ src, const int* __restrict__ dst,
                            const int* __restrict__ rowptr, int* __restrict__ cursor,
                            int* __restrict__ csr_src, int E) {
  int i = blockIdx.x * blockDim.x + threadIdx.x;
  int stride = gridDim.x * blockDim.x;
  for (int e = i; e < E; e += stride) {
    int d = dst[e];
    int pos = atomicAdd(&cursor[d], 1);
    csr_src[rowptr[d] + pos] = src[e];
  }
}

// ---------------- f32 -> bf16 convert (vectorized) ----------------
__global__ void cvt_kernel(const float* __restrict__ in, ushort_t* __restrict__ outb, int total4) {
  int i = blockIdx.x * blockDim.x + threadIdx.x;
  int stride = gridDim.x * blockDim.x;
  const float4* in4 = (const float4*)in;
  for (int idx = i; idx < total4; idx += stride) {
    float4 v = in4[idx];
    ushort4 u;
    u.x = f2bf(v.x); u.y = f2bf(v.y); u.z = f2bf(v.z); u.w = f2bf(v.w);
    ((ushort4*)outb)[idx] = u;
  }
}

// ------- bf16 gather-sum: agg[n] = sum_{j in nbr(n)} hb[j]  (f32 accumulate) -------
// 2 edges per wave-step: half e2 = lane>>5 handles edge i+e2; lane covers col pair c2 = lane&31.
__global__ void gatherb_kernel(const ushort_t* __restrict__ hb, const int* __restrict__ rowptr,
                               const int* __restrict__ csr_src, float* __restrict__ agg, int N) {
  int lane = threadIdx.x & 63;
  int wid = (blockIdx.x * blockDim.x + threadIdx.x) >> 6;
  int nw = (gridDim.x * blockDim.x) >> 6;
  int e2 = lane >> 5;
  int c2 = lane & 31;
  for (int n = wid; n < N; n += nw) {
    int beg = __builtin_amdgcn_readfirstlane(rowptr[n]);
    int end = __builtin_amdgcn_readfirstlane(rowptr[n + 1]);
    float ax0 = 0.f, ay0 = 0.f, ax1 = 0.f, ay1 = 0.f;
    for (int k = beg; k < end; k += 64) {
      int myidx = (k + lane < end) ? csr_src[k + lane] : 0;
      int cnt = end - k; if (cnt > 64) cnt = 64;
      int i = 0;
      for (; i + 3 < cnt; i += 4) {
        int ia = __shfl(myidx, i + e2);
        int ib = __shfl(myidx, i + 2 + e2);
        unsigned int pa = *(const unsigned int*)(hb + (size_t)ia * D + (c2 << 1));
        unsigned int pb = *(const unsigned int*)(hb + (size_t)ib * D + (c2 << 1));
        ax0 += __uint_as_float(pa << 16);
        ay0 += __uint_as_float(pa & 0xffff0000u);
        ax1 += __uint_as_float(pb << 16);
        ay1 += __uint_as_float(pb & 0xffff0000u);
      }
      for (; i < cnt; i += 2) {
        int idxs = (i + e2) & 63;
        int ia = __shfl(myidx, idxs);
        if (i + e2 < cnt) {
          unsigned int pa = *(const unsigned int*)(hb + (size_t)ia * D + (c2 << 1));
          ax0 += __uint_as_float(pa << 16);
          ay0 += __uint_as_float(pa & 0xffff0000u);
        }
      }
    }
    float sx = ax0 + ax1;
    float sy = ay0 + ay1;
    sx += __shfl_xor(sx, 32);
    sy += __shfl_xor(sy, 32);
    if (lane < 32) {
      *(float2*)(agg + (size_t)n * D + (c2 << 1)) = make_float2(sx, sy);
    }
  }
}

// ---------------- fused matmul (R3 structure — unchanged, proven codegen) ----------------
template <int DUAL, int SUMAB, int SCALEA, int MASKB, int RELU, int STATS>
__global__ __launch_bounds__(256, 2)
void mm_kernel(const float* __restrict__ A, const float* __restrict__ B,
               const float* __restrict__ W1, const float* __restrict__ W2,
               const float* __restrict__ bias, const float* __restrict__ deg,
               float* __restrict__ out, float* __restrict__ stats, int N) {
  int j = threadIdx.x & 63;
  int g = threadIdx.x >> 6;

  float w1c[D];
#pragma unroll
  for (int k = 0; k < D; ++k) w1c[k] = W1[k * D + j];
  float w2c[DUAL ? D : 1];
  if constexpr (DUAL) {
#pragma unroll
    for (int k = 0; k < D; ++k) w2c[k] = W2[k * D + j];
  }
  float bj = bias[j];

  float s1 = 0.f, s2 = 0.f;

  for (int tile = blockIdx.x; tile * 64 < N; tile += gridDim.x) {
    int r0 = tile * 64 + g * 16;
    for (int r = 0; r < 16; ++r) {
      int row = __builtin_amdgcn_readfirstlane(r0 + r);
      if (row >= N) break;
      const float4* pa = (const float4*)(A + (size_t)row * D);
      float a0 = 0.f, a1 = 0.f, a2 = 0.f, a3 = 0.f;
#pragma unroll
      for (int k = 0; k < 16; ++k) {
        float4 av = pa[k];
        if constexpr (SUMAB) {
          const float4* pb = (const float4*)(B + (size_t)row * D);
          float4 bv = pb[k];
          av.x += bv.x; av.y += bv.y; av.z += bv.z; av.w += bv.w;
        }
        a0 += av.x * w1c[4 * k + 0];
        a1 += av.y * w1c[4 * k + 1];
        a2 += av.z * w1c[4 * k + 2];
        a3 += av.w * w1c[4 * k + 3];
      }
      float acc = (a0 + a1) + (a2 + a3);
      if constexpr (SCALEA) {
        float dv = deg[row];
        acc *= 1.0f / fmaxf(dv, 1.0f);
      }
      if constexpr (DUAL) {
        const float4* pb = (const float4*)(B + (size_t)row * D);
        float b0 = 0.f, b1 = 0.f, b2 = 0.f, b3 = 0.f;
#pragma unroll
        for (int k = 0; k < 16; ++k) {
          float4 bv = pb[k];
          b0 += bv.x * w2c[4 * k + 0];
          b1 += bv.y * w2c[4 * k + 1];
          b2 += bv.z * w2c[4 * k + 2];
          b3 += bv.w * w2c[4 * k + 3];
        }
        acc += (b0 + b1) + (b2 + b3);
      }
      float bmask = 1.f;
      if constexpr (MASKB) bmask = (deg[row] > 0.f) ? 1.f : 0.f;
      acc += bj * bmask;
      if constexpr (RELU) acc = fmaxf(acc, 0.f);
      out[(size_t)row * D + j] = acc;
      if constexpr (STATS) {
        s1 += acc;
        s2 += acc * acc;
      }
    }
  }

  if constexpr (STATS) {
    __shared__ float red[2][256];
    red[0][threadIdx.x] = s1;
    red[1][threadIdx.x] = s2;
    __syncthreads();
    if (threadIdx.x < 64) {
      int t = threadIdx.x;
      float t1 = red[0][t] + red[0][t + 64] + red[0][t + 128] + red[0][t + 192];
      float t2 = red[1][t] + red[1][t + 64] + red[1][t + 128] + red[1][t + 192];
      atomicAdd(&stats[t], t1);
      atomicAdd(&stats[D + t], t2);
    }
  }
}

// ---------------- BN coef ----------------
__global__ void bn_coef_kernel(const float* __restrict__ stats, const float* __restrict__ gamma,
                               const float* __restrict__ beta, float* __restrict__ coef,
                               float invN) {
  int j = threadIdx.x;
  if (j < D) {
    float mu = stats[j] * invN;
    float var = fmaxf(stats[D + j] * invN - mu * mu, 0.f);
    float rs = rsqrtf(var + 1e-5f);
    float sc = gamma[j] * rs;
    coef[j] = sc;
    coef[D + j] = beta[j] - mu * sc;
  }
}

// ---------------- BN apply + ELU -> f32 h AND bf16 hb ----------------
__global__ void apply_kernel(const float* __restrict__ hpre, const float* __restrict__ coef,
                             float* __restrict__ hout, ushort_t* __restrict__ hb, int total4) {
  int i = blockIdx.x * blockDim.x + threadIdx.x;
  int stride = gridDim.x * blockDim.x;
  const float4* in4 = (const float4*)hpre;
  float4* out4 = (float4*)hout;
  const float4* c4 = (const float4*)coef;
  for (int idx = i; idx < total4; idx += stride) {
    int col4 = idx & 15;
    float4 sc = c4[col4];
    float4 sh = c4[16 + col4];
    float4 v = in4[idx];
    float4 r;
    r.x = v.x * sc.x + sh.x;
    r.y = v.y * sc.y + sh.y;
    r.z = v.z * sc.z + sh.z;
    r.w = v.w * sc.w + sh.w;
    r.x = r.x > 0.f ? r.x : __expf(r.x) - 1.f;
    r.y = r.y > 0.f ? r.y : __expf(r.y) - 1.f;
    r.z = r.z > 0.f ? r.z : __expf(r.z) - 1.f;
    r.w = r.w > 0.f ? r.w : __expf(r.w) - 1.f;
    out4[idx] = r;
    ushort4 u;
    u.x = f2bf(r.x); u.y = f2bf(r.y); u.z = f2bf(r.z); u.w = f2bf(r.w);
    ((ushort4*)hb)[idx] = u;
  }
}

// ---------------- global mean pool ----------------
__global__ void pool_kernel(const float* __restrict__ h, const int* __restrict__ batch,
                            float* __restrict__ pooled, float* __restrict__ pcnt, int N) {
  int lane = threadIdx.x & 63;
  int wid = (blockIdx.x * blockDim.x + threadIdx.x) >> 6;
  int nw = (gridDim.x * blockDim.x) >> 6;
  for (int n = wid; n < N; n += nw) {
    int b = batch[n];
    atomicAdd(&pooled[(size_t)b * D + lane], h[(size_t)n * D + lane]);
    if (lane == 0) atomicAdd(&pcnt[b], 1.0f);
  }
}

// ---------------- head ----------------
__global__ void head_kernel(const float* __restrict__ pooled, const float* __restrict__ pcnt,
                            const float* __restrict__ Wout, const float* __restrict__ bout,
                            float* __restrict__ outp, int G) {
  int idx = blockIdx.x * blockDim.x + threadIdx.x;
  if (idx >= G * 16) return;
  int g = idx >> 4;
  int o = idx & 15;
  float inv = 1.0f / fmaxf(pcnt[g], 1.0f);
  float acc = 0.f;
#pragma unroll
  for (int i = 0; i < D; ++i) acc += pooled[(size_t)g * D + i] * Wout[i * 16 + o];
  outp[idx] = acc * inv + bout[o];
}

extern "C" void kernel_launch(void* const* d_in, const int* in_sizes, int n_in,
                              void* d_out, int out_size, void* d_ws, size_t ws_size,
                              hipStream_t stream) {
  (void)n_in; (void)ws_size;
  const float* x      = (const float*)d_in[0];
  const int*   edge   = (const int*)d_in[1];
  const int*   batch  = (const int*)d_in[2];
  const float* W0     = (const float*)d_in[3];
  const float* b0     = (const float*)d_in[4];
  const float* Wl     = (const float*)d_in[5];
  const float* bl     = (const float*)d_in[6];
  const float* Wr     = (const float*)d_in[7];
  const float* W2a    = (const float*)d_in[8];
  const float* b2a    = (const float*)d_in[9];
  const float* W2b    = (const float*)d_in[10];
  const float* b2b    = (const float*)d_in[11];
  const float* Wrel   = (const float*)d_in[12];
  const float* brel   = (const float*)d_in[13];
  const float* Wroot  = (const float*)d_in[14];
  const float* gammas = (const float*)d_in[15];
  const float* betas  = (const float*)d_in[16];
  const float* Wout   = (const float*)d_in[17];
  const float* bout   = (const float*)d_in[18];
  float* out = (float*)d_out;

  int N = in_sizes[0] / D;
  int E = in_sizes[1] / 2;
  int G = out_size / 16;
  const int* src = edge;
  const int* dst = edge + E;

  float* ws = (float*)d_ws;
  float* bufA = ws;                          // h f32
  float* bufB = bufA + (size_t)N * D;        // agg / GIN tmp
  float* bufC = bufB + (size_t)N * D;        // h_pre
  float* deg  = bufC + (size_t)N * D;        // N
  float* stats = deg + N;                    // 128
  float* coef  = stats + 2 * D;              // 128
  float* pooled = coef + 2 * D;              // G*64
  float* pcnt   = pooled + (size_t)G * D;    // G
  int* hist    = (int*)(pcnt + G);           // N ints (also cursor)
  int* rowptr  = hist + N;                   // N+1 ints
  int* csr_src = rowptr + N + 1;             // E ints
  int* blocksum = csr_src + E;               // 256 ints
  int* blockoff = blocksum + NB_SCAN;        // 256 ints
  ushort_t* hb = (ushort_t*)(blockoff + NB_SCAN);  // N*64 bf16

  int tiles = (N + 63) / 64;
  int total4 = N * D / 4;
  int gather_blocks = (N * 64 + 255) / 256;
  if (gather_blocks > 8192) gather_blocks = 8192;

  // ---- build CSR ----
  hipMemsetAsync(hist, 0, N * sizeof(int), stream);
  hist_kernel<<<1024, 256, 0, stream>>>(dst, hist, E);
  scanA_kernel<<<NB_SCAN, 256, 0, stream>>>(hist, blocksum, N);
  scanB_kernel<<<1, NB_SCAN, 0, stream>>>(blocksum, blockoff, rowptr + N);
  scanC_kernel<<<NB_SCAN, 256, 0, stream>>>(hist, blockoff, rowptr, deg, N);
  hipMemsetAsync(hist, 0, N * sizeof(int), stream);
  fill_kernel<<<1024, 256, 0, stream>>>(src, dst, rowptr, hist, csr_src, E);

  // ---- layer 0: custom_mp ----
  cvt_kernel<<<2048, 256, 0, stream>>>(x, hb, total4);
  gatherb_kernel<<<gather_blocks, 256, 0, stream>>>(hb, rowptr, csr_src, bufB, N);
  hipMemsetAsync(stats, 0, 2 * D * sizeof(float), stream);
  mm_kernel<0, 0, 1, 1, 0, 1><<<tiles, 256, 0, stream>>>(bufB, nullptr, W0, nullptr, b0, deg, bufC, stats, N);
  bn_coef_kernel<<<1, 64, 0, stream>>>(stats, gammas + 0 * D, betas + 0 * D, coef, 1.0f / N);
  apply_kernel<<<2048, 256, 0, stream>>>(bufC, coef, bufA, hb, total4);

  // ---- layer 1: SAGE ----
  gatherb_kernel<<<gather_blocks, 256, 0, stream>>>(hb, rowptr, csr_src, bufB, N);
  hipMemsetAsync(stats, 0, 2 * D * sizeof(float), stream);
  mm_kernel<1, 0, 1, 0, 0, 1><<<tiles, 256, 0, stream>>>(bufB, bufA, Wl, Wr, bl, deg, bufC, stats, N);
  bn_coef_kernel<<<1, 64, 0, stream>>>(stats, gammas + 1 * D, betas + 1 * D, coef, 1.0f / N);
  apply_kernel<<<2048, 256, 0, stream>>>(bufC, coef, bufA, hb, total4);

  // ---- layer 2: GIN ----
  gatherb_kernel<<<gather_blocks, 256, 0, stream>>>(hb, rowptr, csr_src, bufB, N);
  mm_kernel<0, 1, 0, 0, 1, 0><<<tiles, 256, 0, stream>>>(bufB, bufA, W2a, nullptr, b2a, nullptr, bufB, nullptr, N);
  hipMemsetAsync(stats, 0, 2 * D * sizeof(float), stream);
  mm_kernel<0, 0, 0, 0, 0, 1><<<tiles, 256, 0, stream>>>(bufB, nullptr, W2b, nullptr, b2b, nullptr, bufC, stats, N);
  bn_coef_kernel<<<1, 64, 0, stream>>>(stats, gammas + 2 * D, betas + 2 * D, coef, 1.0f / N);
  apply_kernel<<<2048, 256, 0, stream>>>(bufC, coef, bufA, hb, total4);

  // ---- layer 3: GraphConv ----
  gatherb_kernel<<<gather_blocks, 256, 0, stream>>>(hb, rowptr, csr_src, bufB, N);
  hipMemsetAsync(stats, 0, 2 * D * sizeof(float), stream);
  mm_kernel<1, 0, 0, 0, 0, 1><<<tiles, 256, 0, stream>>>(bufB, bufA, Wrel, Wroot, brel, nullptr, bufC, stats, N);
  bn_coef_kernel<<<1, 64, 0, stream>>>(stats, gammas + 3 * D, betas + 3 * D, coef, 1.0f / N);
  apply_kernel<<<2048, 256, 0, stream>>>(bufC, coef, bufA, hb, total4);

  // ---- pool + head ----
  hipMemsetAsync(pooled, 0, (size_t)G * D * sizeof(float), stream);
  hipMemsetAsync(pcnt, 0, G * sizeof(float), stream);
  pool_kernel<<<1024, 256, 0, stream>>>(bufA, batch, pooled, pcnt, N);
  head_kernel<<<(G * 16 + 255) / 256, 256, 0, stream>>>(pooled, pcnt, Wout, bout, out, G);
}